// Round 1
// baseline (235.252 us; speedup 1.0000x reference)
//
#include <hip/hip_runtime.h>
#include <hip/hip_bf16.h>

// DomainEncoder fused: 8-expert MoE MLP, N=32768, 256 -> 1024 (LN+ReLU) -> 256.
// Pipeline:
//   1. transpose W1,W2 -> bf16 [N,K] layout (B^T for MFMA)
//   2. counting-sort rows by domain into 64-row single-domain tiles
//   3. fused_mlp: ONE kernel per 64-row tile (512 thr, 8 waves):
//        phase 0: gather x rows fp32->bf16 into swizzled LDS (kills copy_rows)
//        phase 1: h = x@W1^T, W1 streamed global->reg (per-wave-unique cols,
//                 NO barriers in K-loop), acc fp32 in regs
//        phase 1.5: +b1, LN stats from fp32 acc (cross-wave via LDS), ReLU,
//                 write bf16 H to XOR-swizzled LDS (H never touches HBM)
//        phase 2: out = H@W2^T, A-frags from swizzled LDS, W2 global->reg,
//                 NO barriers in K-loop; scatter fp32 out via perm
//   XCD-chunked block swizzle (520 = 8*65, bijective) for weight L2 locality.
//   s_setprio(1) around MFMA clusters (waves free-run -> T5 regime).

#define ND 8
#define NROWS 32768
#define DIN 256
#define DHID 1024
#define DOUT 256
#define RPT 64                // rows per tile
#define MPAD64 33280          // 32768 + 8*64 worst-case padding
#define NT64 520              // 512 + 8 worst-case tiles (8*65 -> clean swizzle)

typedef short short8 __attribute__((ext_vector_type(8)));
typedef float floatx4 __attribute__((ext_vector_type(4)));

__device__ __forceinline__ unsigned short f2bf(float f) {
    unsigned u = __builtin_bit_cast(unsigned, f);
    unsigned r = u + 0x7fff + ((u >> 16) & 1);   // RNE (inputs finite)
    return (unsigned short)(r >> 16);
}

// ---------------- 1. weight transpose fp32[R,C] -> bf16[C,R], per-domain z ----
__global__ void transpose_bf16(const float* __restrict__ in,
                               unsigned short* __restrict__ out,
                               int R, int C) {
    __shared__ float t[32][33];
    const int z = blockIdx.z;
    const int c0 = blockIdx.x * 32, r0 = blockIdx.y * 32;
    const int tx = threadIdx.x & 31, ty = threadIdx.x >> 5;   // 32x8
    const float* src = in + (size_t)z * R * C;
    unsigned short* dst = out + (size_t)z * R * C;
#pragma unroll
    for (int i = 0; i < 32; i += 8)
        t[ty + i][tx] = src[(size_t)(r0 + ty + i) * C + c0 + tx];
    __syncthreads();
#pragma unroll
    for (int i = 0; i < 32; i += 8)
        dst[(size_t)(c0 + ty + i) * R + r0 + tx] = f2bf(t[tx][ty + i]);
}

// ---------------- 2a. init perm/counters ------------------------------------
__global__ void zero_init(int* __restrict__ perm, int* __restrict__ cnt) {
    int i = blockIdx.x * 256 + threadIdx.x;
    if (i < MPAD64) perm[i] = -1;
    if (i < 16) cnt[i] = 0;            // counts[8] + cursors[8]
}

// ---------------- 2b. histogram (block-aggregated atomics) --------------------
__global__ void histo(const int* __restrict__ dt, int* __restrict__ counts) {
    __shared__ int lc[ND];
    if (threadIdx.x < ND) lc[threadIdx.x] = 0;
    __syncthreads();
    int i = blockIdx.x * 256 + threadIdx.x;      // grid covers exactly NROWS
    atomicAdd(&lc[dt[i]], 1);
    __syncthreads();
    if (threadIdx.x < ND) atomicAdd(&counts[threadIdx.x], lc[threadIdx.x]);
}

// ---------------- 2c. 64-aligned offsets + tile metadata ---------------------
__global__ void make_meta(const int* __restrict__ counts, int* __restrict__ cursors,
                          int2* __restrict__ meta) {
    __shared__ int base[ND], ntc[ND];
    const int t = threadIdx.x;     // 64 threads
    if (t == 0) {
        int off = 0;
        for (int d = 0; d < ND; d++) {
            base[d] = off;
            ntc[d] = (counts[d] + 63) >> 6;
            cursors[d] = off;
            off += ntc[d] << 6;
        }
    }
    __syncthreads();
    for (int i = t; i < NT64; i += 64) {
        int2 m = make_int2(-1, 0);
#pragma unroll
        for (int d = 0; d < ND; d++) {
            const int ti = i - (base[d] >> 6);
            if (ti >= 0 && ti < ntc[d]) m = make_int2(d, base[d] + (ti << 6));
        }
        meta[i] = m;
    }
}

// ---------------- 2d. position assignment: 8 global atomics per 256 rows ------
__global__ __launch_bounds__(256)
void assign_pos(const int* __restrict__ dt, int* __restrict__ cursors,
                int* __restrict__ perm) {
    __shared__ int lcnt[ND];
    __shared__ int lbase[ND];
    const int tid = threadIdx.x;
    if (tid < ND) lcnt[tid] = 0;
    __syncthreads();
    const int r = blockIdx.x * 256 + tid;
    const int d = dt[r];
    const int myrank = atomicAdd(&lcnt[d], 1);   // LDS atomic: cheap
    __syncthreads();
    if (tid < ND && lcnt[tid] > 0)
        lbase[tid] = atomicAdd(&cursors[tid], lcnt[tid]);  // 8 global atomics/block
    __syncthreads();
    perm[lbase[d] + myrank] = r;
}

// ---------------- 3. fused MLP: one 64-row single-domain tile per block -------
__global__ __launch_bounds__(512, 2)
void fused_mlp(const float* __restrict__ x,
               const unsigned short* __restrict__ W1T,   // [8][1024][256] bf16
               const float* __restrict__ b1,             // [8][1024]
               const float* __restrict__ gamma,
               const float* __restrict__ beta,
               const unsigned short* __restrict__ W2T,   // [8][256][1024] bf16
               const float* __restrict__ b2,             // [8][256]
               const int2* __restrict__ meta,
               const int* __restrict__ perm,
               float* __restrict__ out) {
    // XCD-chunked bijective swizzle: 520 = 8 * 65
    const int bid = (int)blockIdx.x;
    const int swz = (bid & 7) * (NT64 >> 3) + (bid >> 3);
    const int2 md = meta[swz];
    const int dom = md.x;
    if (dom < 0) return;
    const int m0 = md.y;

    __shared__ unsigned short Hs[RPT * DHID];   // 128 KB bf16, XOR-swizzled
    __shared__ float red[1024];                 // 4 KB: per-wave partials, then mu/rstd
    unsigned short* Axs = Hs;                   // 64x256 bf16 (32 KB), phase 0/1 only

    const int tid = threadIdx.x;
    const int lane = tid & 63;
    const int w = tid >> 6;          // wave 0..7
    const int l15 = lane & 15;
    const int q = lane >> 4;         // 0..3

    // ---- phase 0: gather x rows fp32 -> bf16 into Axs (swizzled) ----
    {
        const int row = tid >> 3;                  // 64 rows, 8 threads each
        const int c8 = tid & 7;
        const int orig = perm[m0 + row];
        const int sw = (row & 7) << 3;             // short-index XOR (16B slots)
        if (orig >= 0) {
            const float4* src = (const float4*)(x + (size_t)orig * DIN);
#pragma unroll
            for (int it = 0; it < 8; ++it) {
                const int c = it * 8 + c8;         // float4 chunk 0..63
                const float4 v = src[c];
                ushort4 o;
                o.x = f2bf(v.x); o.y = f2bf(v.y); o.z = f2bf(v.z); o.w = f2bf(v.w);
                *(ushort4*)&Axs[(row * DIN + c * 4) ^ sw] = o;
            }
        } else {
            const ushort4 z = {0, 0, 0, 0};
#pragma unroll
            for (int it = 0; it < 8; ++it) {
                const int c = it * 8 + c8;
                *(ushort4*)&Axs[(row * DIN + c * 4) ^ sw] = z;
            }
        }
    }

    // ---- phase 1: h = x @ W1^T, wave w owns cols [w*128, w*128+128) ----
    // B streams global->reg (per-wave-unique), double-buffered; NO barriers in loop.
    const int n0w = w * 128;
    const unsigned short* B1p = W1T + (size_t)dom * DHID * DIN
                              + (size_t)(n0w + l15) * DIN + q * 8;
    short8 bA[8], bB[8];
#pragma unroll
    for (int j = 0; j < 8; ++j)                    // preload k0=0 (before barrier)
        bA[j] = *(const short8*)(B1p + (size_t)j * 16 * DIN);

    __syncthreads();                               // Axs ready

    floatx4 acc[4][8];
#pragma unroll
    for (int i = 0; i < 4; ++i)
#pragma unroll
        for (int j = 0; j < 8; ++j) acc[i][j] = 0.f;

#pragma unroll
    for (int t = 0; t < 8; ++t) {                  // K = 256, step 32
        const int k0 = t * 32;
        short8* bc = (t & 1) ? bB : bA;            // static under full unroll
        short8* bn = (t & 1) ? bA : bB;
        if (t < 7) {
#pragma unroll
            for (int j = 0; j < 8; ++j)
                bn[j] = *(const short8*)(B1p + (size_t)j * 16 * DIN + (k0 + 32));
        }
        short8 a[4];
#pragma unroll
        for (int i = 0; i < 4; ++i) {
            const int row = i * 16 + l15;
            a[i] = *(const short8*)&Axs[(row * DIN + k0 + q * 8) ^ ((row & 7) << 3)];
        }
        __builtin_amdgcn_s_setprio(1);
#pragma unroll
        for (int i = 0; i < 4; ++i)
#pragma unroll
            for (int j = 0; j < 8; ++j)
                acc[i][j] = __builtin_amdgcn_mfma_f32_16x16x32_bf16(a[i], bc[j], acc[i][j], 0, 0, 0);
        __builtin_amdgcn_s_setprio(0);
    }

    // ---- phase 1.5: +b1, LN stats (fp32), normalize+ReLU, write Hs ----
    float b1v[8], gv[8], bv[8];
#pragma unroll
    for (int j = 0; j < 8; ++j) {
        const int col = n0w + j * 16 + l15;
        b1v[j] = b1[dom * DHID + col];
        gv[j]  = gamma[dom * DHID + col];
        bv[j]  = beta[dom * DHID + col];
    }
#pragma unroll
    for (int i = 0; i < 4; ++i)
#pragma unroll
        for (int j = 0; j < 8; ++j)
#pragma unroll
            for (int r = 0; r < 4; ++r) acc[i][j][r] += b1v[j];

    // per-(i,r): sum over 8 col-frags, then 16-lane shuffle reduce (rows live
    // at col=lane&15 varying, row=(lane>>4)*4+reg fixed per lane group)
#pragma unroll
    for (int i = 0; i < 4; ++i)
#pragma unroll
        for (int r = 0; r < 4; ++r) {
            float s = 0.f, s2 = 0.f;
#pragma unroll
            for (int j = 0; j < 8; ++j) {
                const float v = acc[i][j][r];
                s += v; s2 += v * v;
            }
#pragma unroll
            for (int o = 8; o; o >>= 1) {
                s  += __shfl_xor(s, o, 64);
                s2 += __shfl_xor(s2, o, 64);
            }
            if (l15 == 0) {
                const int row = i * 16 + q * 4 + r;
                red[w * 64 + row]       = s;       // per-wave partial (128 cols)
                red[512 + w * 64 + row] = s2;
            }
        }
    __syncthreads();
    if (tid < 64) {                                 // wave 0, lockstep: reads precede writes
        float s = 0.f, s2 = 0.f;
#pragma unroll
        for (int ww = 0; ww < 8; ++ww) {
            s  += red[ww * 64 + tid];
            s2 += red[512 + ww * 64 + tid];
        }
        const float mu  = s * (1.f / 1024.f);
        const float var = fmaxf(s2 * (1.f / 1024.f) - mu * mu, 0.f);
        red[tid]      = mu;
        red[64 + tid] = rsqrtf(var + 1e-5f);
    }
    __syncthreads();

#pragma unroll
    for (int i = 0; i < 4; ++i)
#pragma unroll
        for (int r = 0; r < 4; ++r) {
            const int row = i * 16 + q * 4 + r;
            const float mu   = red[row];
            const float rstd = red[64 + row];
            const int sw = (row & 7) << 3;
#pragma unroll
            for (int j = 0; j < 8; ++j) {
                const int col = n0w + j * 16 + l15;
                const float v = fmaxf((acc[i][j][r] - mu) * rstd * gv[j] + bv[j], 0.f);
                Hs[(row * DHID + col) ^ sw] = f2bf(v);
            }
        }
    __syncthreads();                                // Hs ready (Axs region dead)

    // ---- phase 2: out = Hs @ W2^T, wave w owns cols [w*32, w*32+32) ----
    // A-frags from swizzled LDS, B global->reg double-buffered; NO barriers.
    floatx4 acc2[4][2];
#pragma unroll
    for (int i = 0; i < 4; ++i) { acc2[i][0] = 0.f; acc2[i][1] = 0.f; }

    const int c0w = w * 32;
    const unsigned short* B2p = W2T + (size_t)dom * DOUT * DHID
                              + (size_t)(c0w + l15) * DHID + q * 8;
    short8 cA[2], cB[2];
#pragma unroll
    for (int jj = 0; jj < 2; ++jj)
        cA[jj] = *(const short8*)(B2p + (size_t)jj * 16 * DHID);

    for (int t = 0; t < 32; t += 2) {               // K = 1024, step 32, 2-step body
        const int k0 = t * 32;
        if (t + 1 < 32) {
#pragma unroll
            for (int jj = 0; jj < 2; ++jj)
                cB[jj] = *(const short8*)(B2p + (size_t)jj * 16 * DHID + (k0 + 32));
        }
        {
            short8 a[4];
#pragma unroll
            for (int ii = 0; ii < 4; ++ii) {
                const int row = ii * 16 + l15;
                a[ii] = *(const short8*)&Hs[(row * DHID + k0 + q * 8) ^ ((row & 7) << 3)];
            }
            __builtin_amdgcn_s_setprio(1);
#pragma unroll
            for (int ii = 0; ii < 4; ++ii)
#pragma unroll
                for (int jj = 0; jj < 2; ++jj)
                    acc2[ii][jj] = __builtin_amdgcn_mfma_f32_16x16x32_bf16(a[ii], cA[jj], acc2[ii][jj], 0, 0, 0);
            __builtin_amdgcn_s_setprio(0);
        }
        if (t + 2 < 32) {
#pragma unroll
            for (int jj = 0; jj < 2; ++jj)
                cA[jj] = *(const short8*)(B2p + (size_t)jj * 16 * DHID + (k0 + 64));
        }
        {
            short8 a[4];
#pragma unroll
            for (int ii = 0; ii < 4; ++ii) {
                const int row = ii * 16 + l15;
                a[ii] = *(const short8*)&Hs[(row * DHID + k0 + 32 + q * 8) ^ ((row & 7) << 3)];
            }
            __builtin_amdgcn_s_setprio(1);
#pragma unroll
            for (int ii = 0; ii < 4; ++ii)
#pragma unroll
                for (int jj = 0; jj < 2; ++jj)
                    acc2[ii][jj] = __builtin_amdgcn_mfma_f32_16x16x32_bf16(a[ii], cB[jj], acc2[ii][jj], 0, 0, 0);
            __builtin_amdgcn_s_setprio(0);
        }
    }

    // ---- epilogue: scatter out = acc2 + b2 via perm (padding rows skipped) ----
    float b2v[2];
#pragma unroll
    for (int jj = 0; jj < 2; ++jj)
        b2v[jj] = b2[dom * DOUT + c0w + jj * 16 + l15];
#pragma unroll
    for (int ii = 0; ii < 4; ++ii)
#pragma unroll
        for (int r = 0; r < 4; ++r) {
            const int row = ii * 16 + q * 4 + r;
            const int orig = perm[m0 + row];
            if (orig < 0) continue;
#pragma unroll
            for (int jj = 0; jj < 2; ++jj)
                out[(size_t)orig * DOUT + c0w + jj * 16 + l15] = acc2[ii][jj][r] + b2v[jj];
        }
}

// ---------------- launch ------------------------------------------------------
extern "C" void kernel_launch(void* const* d_in, const int* in_sizes, int n_in,
                              void* d_out, int out_size, void* d_ws, size_t ws_size,
                              hipStream_t stream) {
    const float* x = (const float*)d_in[0];
    const int* dt = (const int*)d_in[1];
    const float* W1 = (const float*)d_in[2];
    const float* b1 = (const float*)d_in[3];
    const float* gamma = (const float*)d_in[4];
    const float* beta = (const float*)d_in[5];
    const float* W2 = (const float*)d_in[6];
    const float* b2 = (const float*)d_in[7];
    float* out = (float*)d_out;

    char* ws = (char*)d_ws;
    size_t off = 0;
    auto take = [&](size_t nbytes) -> char* {
        char* p = ws + off;
        off = (off + nbytes + 255) & ~(size_t)255;
        return p;
    };
    unsigned short* W1T = (unsigned short*)take((size_t)ND * DHID * DIN * 2);   // [8,1024,256]
    unsigned short* W2T = (unsigned short*)take((size_t)ND * DOUT * DHID * 2);  // [8,256,1024]
    int* PERM = (int*)take(MPAD64 * 4);
    int* CNT  = (int*)take(64);            // counts[8] then cursors[8]
    int2* META = (int2*)take(NT64 * 8);
    (void)ws_size; (void)n_in; (void)in_sizes; (void)out_size;

    int* COUNTS = CNT;
    int* CURSORS = CNT + 8;

    transpose_bf16<<<dim3(DHID / 32, DIN / 32, ND), 256, 0, stream>>>(W1, W1T, DIN, DHID);
    transpose_bf16<<<dim3(DOUT / 32, DHID / 32, ND), 256, 0, stream>>>(W2, W2T, DHID, DOUT);
    zero_init<<<MPAD64 / 256, 256, 0, stream>>>(PERM, CNT);
    histo<<<NROWS / 256, 256, 0, stream>>>(dt, COUNTS);
    make_meta<<<1, 64, 0, stream>>>(COUNTS, CURSORS, META);
    assign_pos<<<NROWS / 256, 256, 0, stream>>>(dt, CURSORS, PERM);
    fused_mlp<<<NT64, 512, 0, stream>>>(x, W1T, b1, gamma, beta, W2T, b2, META, PERM, out);
}